// Round 10
// baseline (699.306 us; speedup 1.0000x reference)
//
#include <hip/hip_runtime.h>
#include <hip/hip_bf16.h>

#define NPTS 100000
#define NPTS_PAD 100096
#define DHID 512
#define EPSV 1e-5f

typedef __attribute__((ext_vector_type(4))) float f32x4;

// ---- workspace layout (bytes) ----
// Operands k-tiled in fp8 e4m3: Xp/Hp = [KD/64][NPTS_PAD][64] bytes, Wp = [KD/64][512][64]
#define OFF_INBF   0UL            // 2*100096*64 = 12,812,288
#define OFF_W0     12812288UL     // 2*512*64    = 65,536
#define OFF_W1     12877824UL     // 8*512*64    = 262,144
#define OFF_W2     13139968UL     // 262,144
#define OFF_C0     13402112UL     // 512*4 (pad to 2048)
#define OFF_C1     13404160UL
#define OFF_C2     13406208UL
#define OFF_PARTS  13408256UL     // 1563*512*4 = 3,201,024
#define OFF_PARTS2 16609280UL     // 64*512*4 = 131,072
#define OFF_PARTS3 16740352UL     // 8*512*4 = 16,384
#define OFF_H1     16756736UL     // 8*100096*64 = 51,249,152
#define OFF_H2     68005888UL     // 51,249,152  (end 119,255,040)

typedef const __attribute__((address_space(1))) unsigned int* gp_t;
typedef __attribute__((address_space(3))) unsigned int* lp_t;

__device__ __forceinline__ void async_copy16(const void* g, void* l) {
    __builtin_amdgcn_global_load_lds((gp_t)g, (lp_t)l, 16, 0, 0);
}

// pack 4 floats -> 4 fp8 e4m3 bytes (RNE, v_cvt_pk_fp8_f32)
__device__ __forceinline__ unsigned pack4_fp8(float a, float b, float c, float d) {
    unsigned v = (unsigned)__builtin_amdgcn_cvt_pk_fp8_f32(a, b, 0, false);
    v = (unsigned)__builtin_amdgcn_cvt_pk_fp8_f32(c, d, (int)v, true);
    return v;
}

// ---------- prep: fp32 [NPTS][128] -> fp8 [2][NPTS_PAD][64] ----------
__global__ __launch_bounds__(256) void cvt_pack_kernel(const float* __restrict__ in,
                                                       unsigned char* __restrict__ out) {
    long total = (long)NPTS * 2;
    long stride = (long)gridDim.x * blockDim.x;
    for (long idx = (long)blockIdx.x * blockDim.x + threadIdx.x; idx < total; idx += stride) {
        int kt = (int)(idx / NPTS);
        long r = idx - (long)kt * NPTS;
        const float* src = in + r * 128 + kt * 64;
        unsigned dw[16];
#pragma unroll
        for (int j = 0; j < 16; ++j)
            dw[j] = pack4_fp8(src[4 * j], src[4 * j + 1], src[4 * j + 2], src[4 * j + 3]);
        uint4* dst = (uint4*)(out + ((long)kt * NPTS_PAD + r) * 64);
#pragma unroll
        for (int j = 0; j < 4; ++j)
            dst[j] = make_uint4(dw[4 * j], dw[4 * j + 1], dw[4 * j + 2], dw[4 * j + 3]);
    }
}

// ---------- prep: all three packed W = fp8(A - B) in ONE dispatch ----------
__global__ __launch_bounds__(256) void wdiff_all_kernel(const float* __restrict__ A0,
                                                        const float* __restrict__ B0,
                                                        const float* __restrict__ A1,
                                                        const float* __restrict__ B1,
                                                        const float* __restrict__ A2,
                                                        const float* __restrict__ B2,
                                                        unsigned char* __restrict__ W0,
                                                        unsigned char* __restrict__ W1,
                                                        unsigned char* __restrict__ W2) {
    int idx = blockIdx.x * 256 + threadIdx.x;
    const float *A, *B; unsigned char* W; int KD, u;
    if (idx < 1024)      { A = A0; B = B0; W = W0; KD = 128; u = idx; }
    else if (idx < 5120) { A = A1; B = B1; W = W1; KD = 512; u = idx - 1024; }
    else                 { A = A2; B = B2; W = W2; KD = 512; u = idx - 5120; if (u >= 4096) return; }
    int kt = u >> 9, row = u & 511;
    const float* sa = A + (long)row * KD + kt * 64;
    const float* sb = B + (long)row * KD + kt * 64;
    unsigned dw[16];
#pragma unroll
    for (int j = 0; j < 16; ++j)
        dw[j] = pack4_fp8(sa[4 * j] - sb[4 * j], sa[4 * j + 1] - sb[4 * j + 1],
                          sa[4 * j + 2] - sb[4 * j + 2], sa[4 * j + 3] - sb[4 * j + 3]);
    uint4* dst = (uint4*)(W + ((long)kt * 512 + row) * 64);
#pragma unroll
    for (int j = 0; j < 4; ++j)
        dst[j] = make_uint4(dw[4 * j], dw[4 * j + 1], dw[4 * j + 2], dw[4 * j + 3]);
}

// ---------- colsum of in_set (fp32, deterministic 2-stage) ----------
__global__ __launch_bounds__(256) void colsum_in_kernel(const float* __restrict__ in,
                                                        float* __restrict__ parts) {
    __shared__ float sh[256];
    int t = threadIdx.x, blk = blockIdx.x;
    int c = t & 127, half = t >> 7;
    long rbeg = (long)blk * 196 + half;
    long rend = (long)(blk + 1) * 196; if (rend > NPTS) rend = NPTS;
    float s = 0.f;
    for (long r = rbeg; r < rend; r += 2) s += in[r * 128 + c];
    sh[t] = s;
    __syncthreads();
    if (t < 128) parts[blk * 128 + t] = sh[t] + sh[t + 128];
}

// ---------- generic partial reduce ----------
__global__ void part_reduceW_kernel(const float* __restrict__ parts, int nparts, int width,
                                    int op, float* __restrict__ out) {
    int g = blockIdx.x, t = threadIdx.x;
    int chunk = (nparts + gridDim.x - 1) / gridDim.x;
    int b0 = g * chunk, b1 = b0 + chunk; if (b1 > nparts) b1 = nparts;
    float s = 0.f;
    for (int b = b0; b < b1; ++b) {
        float v = parts[(long)b * width + t];
        s = (op == 0) ? (s + v) : fmaxf(s, v);
    }
    out[(long)g * width + t] = s;
}

// ---------- fold 8 partial rows + GEMV ----------
__global__ __launch_bounds__(64) void gemv_fold_kernel(const float* __restrict__ p3, int dsum,
                                                       const float* __restrict__ Bm,
                                                       const float* __restrict__ bias, int op,
                                                       float* __restrict__ out) {
    int j = blockIdx.x, t = threadIdx.x;
    float acc = 0.f;
    for (int d = t; d < dsum; d += 64) {
        float s = 0.f;
#pragma unroll
        for (int g = 0; g < 8; ++g) {
            float v = p3[(long)g * dsum + d];
            s = (op == 0) ? (s + v) : fmaxf(s, v);
        }
        acc += s * Bm[(long)j * dsum + d];
    }
#pragma unroll
    for (int m = 32; m >= 1; m >>= 1) acc += __shfl_down(acc, m);
    if (t == 0) out[j] = acc + (bias ? bias[j] : 0.0f);
}

// ---------- fused layer (fp8) — R7 production body + DIAG ablation variants ----------
// DIAG: 0=production (REP=1). Diagnostics (grid=256, scratch out, REP scales dur):
//  1: loop + mini-epilogue, REP=4
//  2: loop w/o staging (stage tiles 0,1 once; no vmcnt), REP=6
//  3: loop w/o MFMA (VALU keep-alive), REP=6
//  4: pure MFMA (no staging/ds_read/barriers in loop), REP=10
template<int KD, bool STORE, int REDOP, int DIAG = 0>
__global__ __launch_bounds__(512, 2)
void layer_kernel(const unsigned char* __restrict__ Xp, const unsigned char* __restrict__ Wp,
                  const float* __restrict__ cvec, const float* __restrict__ gvec,
                  const float* __restrict__ bvec, unsigned char* __restrict__ Hout,
                  float* __restrict__ red_out) {
    static_assert(KD % 64 == 0, "");
    constexpr int NK = KD / 64;
    constexpr int REP = (DIAG == 0) ? 1 : (DIAG == 1) ? 4 : (DIAG == 4) ? 10 : 6;
    constexpr bool DO_STAGE = (DIAG != 2 && DIAG != 4);
    __shared__ __align__(128) char smem[3 * 40960];

    const int t = threadIdx.x;
    const int lane = t & 63;
    const int wid = t >> 6;
    const int wm = wid >> 2;
    const int wn = wid & 3;
    const int ln15 = lane & 15;
    const int lg = lane >> 4;
    const long row0 = (long)blockIdx.x * 128;

    f32x4 acc[4][8];
#pragma unroll
    for (int i = 0; i < 4; ++i)
#pragma unroll
        for (int j = 0; j < 8; ++j) acc[i][j] = (f32x4){0.f, 0.f, 0.f, 0.f};

    const int l4 = lane >> 2;
    const int soff = ((lane & 3) ^ ((lane >> 3) & 3)) * 16;
    const char* Xbase = (const char*)Xp + (row0 + wid * 16 + l4) * 64 + soff;
    const char* Wbase = (const char*)Wp + (wid * 4096 + l4 * 64) + soff;

    auto stage = [&](int ks) {
        char* Xs = smem + (ks % 3) * 40960;
        char* Ws = Xs + 8192;
        async_copy16(Xbase + (long)ks * (NPTS_PAD * 64), Xs + wid * 1024 + lane * 16);
#pragma unroll
        for (int q = 0; q < 4; ++q)
            async_copy16(Wbase + ks * 32768 + q * 1024,
                         Ws + wid * 4096 + q * 1024 + lane * 16);
    };

#define RD8(BASE, r, ksub) (*(const long*)((BASE) + (r) * 64 + \
        (((((ksub) * 2 + (lg >> 1)) ^ (((r) >> 1) & 3)) * 16) + (lg & 1) * 8)))

    for (int rep = 0; rep < REP; ++rep) {
        if constexpr (DO_STAGE) {
            stage(0);
            if (NK > 1) stage(1);
            if (NK > 2) stage(2);
        } else {
            if (rep == 0) {
                stage(0);
                if (NK > 1) stage(1);
                asm volatile("s_waitcnt vmcnt(0)" ::: "memory");
                __builtin_amdgcn_s_barrier();
            }
        }

        if constexpr (DIAG == 4) {
            // pure-MFMA floor: operands hoisted from buf0, no sync in loop
            const char* Xs = smem;
            const char* Ws = smem + 8192;
            long a0[4], a1[4], b0[8], b1[8];
#pragma unroll
            for (int fm = 0; fm < 4; ++fm) {
                int r = wm * 64 + fm * 16 + ln15;
                a0[fm] = RD8(Xs, r, 0); a1[fm] = RD8(Xs, r, 1);
            }
#pragma unroll
            for (int fn = 0; fn < 8; ++fn) {
                int r = wn * 128 + fn * 16 + ln15;
                b0[fn] = RD8(Ws, r, 0); b1[fn] = RD8(Ws, r, 1);
            }
            __builtin_amdgcn_s_setprio(1);
#pragma unroll
            for (int ks = 0; ks < NK; ++ks) {
#pragma unroll
                for (int fm = 0; fm < 4; ++fm)
#pragma unroll
                    for (int fn = 0; fn < 8; ++fn)
                        acc[fm][fn] = __builtin_amdgcn_mfma_f32_16x16x32_fp8_fp8(a0[fm], b0[fn], acc[fm][fn], 0, 0, 0);
#pragma unroll
                for (int fm = 0; fm < 4; ++fm)
#pragma unroll
                    for (int fn = 0; fn < 8; ++fn)
                        acc[fm][fn] = __builtin_amdgcn_mfma_f32_16x16x32_fp8_fp8(a1[fm], b1[fn], acc[fm][fn], 0, 0, 0);
            }
            __builtin_amdgcn_s_setprio(0);
        } else {
#pragma unroll
            for (int ks = 0; ks < NK; ++ks) {
                if constexpr (DO_STAGE) {
                    if (ks <= NK - 3)      asm volatile("s_waitcnt vmcnt(10)" ::: "memory");
                    else if (ks == NK - 2) asm volatile("s_waitcnt vmcnt(5)" ::: "memory");
                    else                   asm volatile("s_waitcnt vmcnt(0)" ::: "memory");
                }
                __builtin_amdgcn_s_barrier();

                const char* Xs = smem + (ks % 3) * 40960;
                const char* Ws = Xs + 8192;
                long a0[4], a1[4], b0[8], b1[8];
#pragma unroll
                for (int fm = 0; fm < 4; ++fm) {
                    int r = wm * 64 + fm * 16 + ln15;
                    a0[fm] = RD8(Xs, r, 0); a1[fm] = RD8(Xs, r, 1);
                }
#pragma unroll
                for (int fn = 0; fn < 8; ++fn) {
                    int r = wn * 128 + fn * 16 + ln15;
                    b0[fn] = RD8(Ws, r, 0); b1[fn] = RD8(Ws, r, 1);
                }
                if constexpr (DIAG != 3) {
                    __builtin_amdgcn_s_setprio(1);
#pragma unroll
                    for (int fm = 0; fm < 4; ++fm)
#pragma unroll
                        for (int fn = 0; fn < 8; ++fn)
                            acc[fm][fn] = __builtin_amdgcn_mfma_f32_16x16x32_fp8_fp8(a0[fm], b0[fn], acc[fm][fn], 0, 0, 0);
#pragma unroll
                    for (int fm = 0; fm < 4; ++fm)
#pragma unroll
                        for (int fn = 0; fn < 8; ++fn)
                            acc[fm][fn] = __builtin_amdgcn_mfma_f32_16x16x32_fp8_fp8(a1[fm], b1[fn], acc[fm][fn], 0, 0, 0);
                    __builtin_amdgcn_s_setprio(0);
                } else {
                    // VALU keep-alive: consumes a0/a1/b0/b1, feeds acc
#pragma unroll
                    for (int fm = 0; fm < 4; ++fm)
#pragma unroll
                        for (int fn = 0; fn < 8; ++fn) {
                            acc[fm][fn][0] += (float)(int)a0[fm] + (float)(int)b0[fn];
                            acc[fm][fn][1] += (float)(int)a1[fm] + (float)(int)b1[fn];
                        }
                }

                asm volatile("s_waitcnt lgkmcnt(0)" ::: "memory");
                __builtin_amdgcn_sched_barrier(0);
                __builtin_amdgcn_s_barrier();
                __builtin_amdgcn_sched_barrier(0);
                if constexpr (DO_STAGE) {
                    if (ks + 3 < NK) stage(ks + 3);
                }
            }
        }
    }
#undef RD8

    if constexpr (DIAG != 0) {
        // mini-epilogue: keep every acc element (and thus every MFMA) live
        float s = 0.f;
#pragma unroll
        for (int fm = 0; fm < 4; ++fm)
#pragma unroll
            for (int fn = 0; fn < 8; ++fn)
                s += acc[fm][fn][0] + acc[fm][fn][1] + acc[fm][fn][2] + acc[fm][fn][3];
        red_out[(long)blockIdx.x * 512 + t] = s;
        return;
    }

    __syncthreads();

    // ---------------- epilogue (production, byte-identical to R7) ----------------
    float* lnred_s = (float*)smem;
    float* lnred_q = (float*)(smem + 2048);
    float* lnmv    = (float*)(smem + 4096);
    float* csred   = (float*)(smem + 5120);

    const int cbase = wn * 128 + ln15;
    float cv[8], gv[8], bv[8];
#pragma unroll
    for (int fn = 0; fn < 8; ++fn) {
        int col = cbase + fn * 16;
        cv[fn] = cvec[col]; gv[fn] = gvec[col]; bv[fn] = bvec[col];
    }

#pragma unroll
    for (int fm = 0; fm < 4; ++fm)
#pragma unroll
        for (int fn = 0; fn < 8; ++fn) acc[fm][fn] += cv[fn];

    float rs[16], rq[16];
#pragma unroll
    for (int fm = 0; fm < 4; ++fm)
#pragma unroll
        for (int j = 0; j < 4; ++j) {
            float s = 0.f, q = 0.f;
#pragma unroll
            for (int fn = 0; fn < 8; ++fn) {
                float x = acc[fm][fn][j];
                s += x; q += x * x;
            }
            rs[fm * 4 + j] = s; rq[fm * 4 + j] = q;
        }
#pragma unroll
    for (int m = 1; m < 16; m <<= 1)
#pragma unroll
        for (int i = 0; i < 16; ++i) {
            rs[i] += __shfl_xor(rs[i], m);
            rq[i] += __shfl_xor(rq[i], m);
        }
    if (ln15 == 0) {
#pragma unroll
        for (int fm = 0; fm < 4; ++fm)
#pragma unroll
            for (int j = 0; j < 4; ++j) {
                int row = wm * 64 + fm * 16 + lg * 4 + j;
                lnred_s[row * 4 + wn] = rs[fm * 4 + j];
                lnred_q[row * 4 + wn] = rq[fm * 4 + j];
            }
    }
    __syncthreads();
    if (t < 128) {
        float s = lnred_s[t * 4] + lnred_s[t * 4 + 1] + lnred_s[t * 4 + 2] + lnred_s[t * 4 + 3];
        float q = lnred_q[t * 4] + lnred_q[t * 4 + 1] + lnred_q[t * 4 + 2] + lnred_q[t * 4 + 3];
        float mu = s * (1.0f / 512.0f);
        float var = q * (1.0f / 512.0f) - mu * mu;
        lnmv[t * 2] = mu;
        lnmv[t * 2 + 1] = rsqrtf(var + EPSV);
    }
    __syncthreads();

#pragma unroll
    for (int fm = 0; fm < 4; ++fm)
#pragma unroll
        for (int j = 0; j < 4; ++j) {
            int rloc = wm * 64 + fm * 16 + lg * 4 + j;
            long rglob = row0 + rloc;
            bool ok = rglob < NPTS;
            float mu = lnmv[rloc * 2], rstd = lnmv[rloc * 2 + 1];
#pragma unroll
            for (int fn = 0; fn < 8; ++fn) {
                float y = fmaxf((acc[fm][fn][j] - mu) * rstd * gv[fn] + bv[fn], 0.0f);
                acc[fm][fn][j] = ok ? y : 0.0f;
            }
            if (STORE && ok) {
#pragma unroll
                for (int p = 0; p < 4; ++p) {
                    unsigned u = (unsigned)__builtin_amdgcn_cvt_pk_fp8_f32(
                        acc[fm][2 * p][j], acc[fm][2 * p + 1][j], 0, false);
                    int fnA = 2 * p, fnB = 2 * p + 1;
                    Hout[((long)(wn * 2 + (fnA >> 2)) * NPTS_PAD + rglob) * 64 +
                         (fnA & 3) * 16 + ln15] = (unsigned char)(u & 0xff);
                    Hout[((long)(wn * 2 + (fnB >> 2)) * NPTS_PAD + rglob) * 64 +
                         (fnB & 3) * 16 + ln15] = (unsigned char)((u >> 8) & 0xff);
                }
            }
        }

    float cp[8];
#pragma unroll
    for (int fn = 0; fn < 8; ++fn) {
        float p = 0.f;
#pragma unroll
        for (int fm = 0; fm < 4; ++fm)
#pragma unroll
            for (int j = 0; j < 4; ++j) {
                float v = acc[fm][fn][j];
                p = (REDOP == 0) ? (p + v) : fmaxf(p, v);
            }
        cp[fn] = p;
    }
#pragma unroll
    for (int m = 16; m < 64; m <<= 1)
#pragma unroll
        for (int fn = 0; fn < 8; ++fn) {
            float o = __shfl_xor(cp[fn], m);
            cp[fn] = (REDOP == 0) ? (cp[fn] + o) : fmaxf(cp[fn], o);
        }
    if (lg == 0) {
#pragma unroll
        for (int fn = 0; fn < 8; ++fn)
            csred[wm * 512 + wn * 128 + fn * 16 + ln15] = cp[fn];
    }
    __syncthreads();
    {
        float a0v = csred[t], a1v = csred[512 + t];
        red_out[(long)blockIdx.x * 512 + t] = (REDOP == 0) ? (a0v + a1v) : fmaxf(a0v, a1v);
    }
}

extern "C" void kernel_launch(void* const* d_in, const int* in_sizes, int n_in,
                              void* d_out, int out_size, void* d_ws, size_t ws_size,
                              hipStream_t stream) {
    const float* in_set = (const float*)d_in[0];
    const float* A0 = (const float*)d_in[1];
    const float* B0 = (const float*)d_in[2];
    const float* A1 = (const float*)d_in[3];
    const float* B1 = (const float*)d_in[4];
    const float* A2 = (const float*)d_in[5];
    const float* B2 = (const float*)d_in[6];
    const float* ga = (const float*)d_in[7];
    const float* be = (const float*)d_in[8];
    const float* ow = (const float*)d_in[9];
    const float* ob = (const float*)d_in[10];
    float* outp = (float*)d_out;
    char* ws = (char*)d_ws;

    unsigned char* in_f8 = (unsigned char*)(ws + OFF_INBF);
    unsigned char* W0p = (unsigned char*)(ws + OFF_W0);
    unsigned char* W1p = (unsigned char*)(ws + OFF_W1);
    unsigned char* W2p = (unsigned char*)(ws + OFF_W2);
    float* c0 = (float*)(ws + OFF_C0);
    float* c1 = (float*)(ws + OFF_C1);
    float* c2 = (float*)(ws + OFF_C2);
    float* parts = (float*)(ws + OFF_PARTS);
    float* parts2 = (float*)(ws + OFF_PARTS2);
    float* parts3 = (float*)(ws + OFF_PARTS3);
    unsigned char* h1 = (unsigned char*)(ws + OFF_H1);
    unsigned char* h2 = (unsigned char*)(ws + OFF_H2);

    const int nblk = (NPTS + 127) / 128;  // 782

    // ---------------- production (R7 verbatim) ----------------
    cvt_pack_kernel<<<1024, 256, 0, stream>>>(in_set, in_f8);
    wdiff_all_kernel<<<36, 256, 0, stream>>>(A0, B0, A1, B1, A2, B2, W0p, W1p, W2p);

    colsum_in_kernel<<<512, 256, 0, stream>>>(in_set, parts);
    part_reduceW_kernel<<<64, 128, 0, stream>>>(parts, 512, 128, 0, parts2);
    part_reduceW_kernel<<<8, 128, 0, stream>>>(parts2, 64, 128, 0, parts3);
    gemv_fold_kernel<<<512, 64, 0, stream>>>(parts3, 128, B0, nullptr, 0, c0);

    layer_kernel<128, true, 0><<<nblk, 512, 0, stream>>>(in_f8, W0p, c0, ga, be, h1, parts);
    part_reduceW_kernel<<<64, 512, 0, stream>>>(parts, nblk, 512, 0, parts2);
    part_reduceW_kernel<<<8, 512, 0, stream>>>(parts2, 64, 512, 0, parts3);
    gemv_fold_kernel<<<512, 64, 0, stream>>>(parts3, 512, B1, nullptr, 0, c1);

    layer_kernel<512, true, 0><<<nblk, 512, 0, stream>>>(h1, W1p, c1, ga, be, h2, parts);
    part_reduceW_kernel<<<64, 512, 0, stream>>>(parts, nblk, 512, 0, parts2);
    part_reduceW_kernel<<<8, 512, 0, stream>>>(parts2, 64, 512, 0, parts3);
    gemv_fold_kernel<<<512, 64, 0, stream>>>(parts3, 512, B2, nullptr, 0, c2);

    layer_kernel<512, false, 1><<<nblk, 512, 0, stream>>>(h2, W2p, c2, ga, be, nullptr, parts);
    part_reduceW_kernel<<<64, 512, 0, stream>>>(parts, nblk, 512, 1, parts2);
    part_reduceW_kernel<<<8, 512, 0, stream>>>(parts2, 64, 512, 1, parts3);
    gemv_fold_kernel<<<256, 64, 0, stream>>>(parts3, 512, ow, ob, 1, outp);

    // ---------------- diagnostics (scratch-only, after d_out finalized) ----------------
    // grid=256 = exactly 1 block/CU; dur = per-round cost x REP. Writes only `parts`/
    // reads h2/W2p/c2 which are stable within a replay -> deterministic d_out unaffected.
    layer_kernel<512, false, 1, 1><<<256, 512, 0, stream>>>(h2, W2p, c2, ga, be, nullptr, parts); // V1 loop+miniepi  R4
    layer_kernel<512, false, 1, 2><<<256, 512, 0, stream>>>(h2, W2p, c2, ga, be, nullptr, parts); // V2 -staging      R6
    layer_kernel<512, false, 1, 3><<<256, 512, 0, stream>>>(h2, W2p, c2, ga, be, nullptr, parts); // V3 -MFMA         R6
    layer_kernel<512, false, 1, 4><<<256, 512, 0, stream>>>(h2, W2p, c2, ga, be, nullptr, parts); // V4 pure MFMA     R10
}

// Round 11
// 278.030 us; speedup vs baseline: 2.5152x; 2.5152x over previous
//
#include <hip/hip_runtime.h>
#include <hip/hip_bf16.h>

#define NPTS 100000
#define NPTS_PAD 100096
#define DHID 512
#define EPSV 1e-5f

typedef __attribute__((ext_vector_type(4))) float f32x4;

// ---- workspace layout (bytes) ----
// X/H k-tiled fp8 e4m3: [KD/64][NPTS_PAD][64] bytes.
// W register-path fp8: Wpack[wave(4)][frag(NK*16)][lane(64)] u64, frag = ks*16 + fn*2 + s;
//   value = 8 fp8 of (A-B)[col = wave*128 + fn*16 + (lane&15)][k = ks*64 + s*32 + (lane>>4)*8)
#define OFF_INBF   0UL            // 2*100096*64 = 12,812,288
#define OFF_W0     12812288UL     // 4*2*16*64*8 = 65,536
#define OFF_W1     12877824UL     // 4*8*16*64*8 = 262,144
#define OFF_W2     13139968UL     // 262,144
#define OFF_C0     13402112UL     // 512*4 (pad to 2048)
#define OFF_C1     13404160UL
#define OFF_C2     13406208UL
#define OFF_PARTS  13408256UL     // 1563*512*4 = 3,201,024
#define OFF_PARTS2 16609280UL     // 64*512*4 = 131,072
#define OFF_PARTS3 16740352UL     // 8*512*4 = 16,384
#define OFF_H1     16756736UL     // 8*100096*64 = 51,249,152
#define OFF_H2     68005888UL     // 51,249,152  (end 119,255,040)

typedef const __attribute__((address_space(1))) unsigned int* gp_t;
typedef __attribute__((address_space(3))) unsigned int* lp_t;

__device__ __forceinline__ void async_copy16(const void* g, void* l) {
    __builtin_amdgcn_global_load_lds((gp_t)g, (lp_t)l, 16, 0, 0);
}

// pack 4 floats -> 4 fp8 e4m3 bytes (RNE, v_cvt_pk_fp8_f32)
__device__ __forceinline__ unsigned pack4_fp8(float a, float b, float c, float d) {
    unsigned v = (unsigned)__builtin_amdgcn_cvt_pk_fp8_f32(a, b, 0, false);
    v = (unsigned)__builtin_amdgcn_cvt_pk_fp8_f32(c, d, (int)v, true);
    return v;
}

// ---------- prep: fp32 [NPTS][128] -> fp8 [2][NPTS_PAD][64] ----------
__global__ __launch_bounds__(256) void cvt_pack_kernel(const float* __restrict__ in,
                                                       unsigned char* __restrict__ out) {
    long total = (long)NPTS * 2;
    long stride = (long)gridDim.x * blockDim.x;
    for (long idx = (long)blockIdx.x * blockDim.x + threadIdx.x; idx < total; idx += stride) {
        int kt = (int)(idx / NPTS);
        long r = idx - (long)kt * NPTS;
        const float* src = in + r * 128 + kt * 64;
        unsigned dw[16];
#pragma unroll
        for (int j = 0; j < 16; ++j)
            dw[j] = pack4_fp8(src[4 * j], src[4 * j + 1], src[4 * j + 2], src[4 * j + 3]);
        uint4* dst = (uint4*)(out + ((long)kt * NPTS_PAD + r) * 64);
#pragma unroll
        for (int j = 0; j < 4; ++j)
            dst[j] = make_uint4(dw[4 * j], dw[4 * j + 1], dw[4 * j + 2], dw[4 * j + 3]);
    }
}

// ---------- prep: Wpack = fp8(A - B) for all three layers, register-path layout ----------
// u = ((wv*NK + ks)*16 + fn*2 + s)*64 + lane. W0: 8192 u64, W1/W2: 32768 each -> 73728.
__global__ __launch_bounds__(256) void wpack_all_kernel(const float* __restrict__ A0,
                                                        const float* __restrict__ B0,
                                                        const float* __restrict__ A1,
                                                        const float* __restrict__ B1,
                                                        const float* __restrict__ A2,
                                                        const float* __restrict__ B2,
                                                        unsigned long long* __restrict__ W0,
                                                        unsigned long long* __restrict__ W1,
                                                        unsigned long long* __restrict__ W2) {
    int idx = blockIdx.x * 256 + threadIdx.x;
    const float *A, *B; unsigned long long* W; int NK, u;
    if (idx < 8192)       { A = A0; B = B0; W = W0; NK = 2; u = idx; }
    else if (idx < 40960) { A = A1; B = B1; W = W1; NK = 8; u = idx - 8192; }
    else                  { A = A2; B = B2; W = W2; NK = 8; u = idx - 40960; if (u >= 32768) return; }
    int KD = NK * 64;
    int lane = u & 63;
    int rest = u >> 6;
    int s = rest & 1;
    int fn = (rest >> 1) & 7;
    int ks = (rest >> 4) % NK;
    int wv = (rest >> 4) / NK;
    int row = wv * 128 + fn * 16 + (lane & 15);
    int kb = ks * 64 + s * 32 + (lane >> 4) * 8;
    const float* sa = A + (long)row * KD + kb;
    const float* sb = B + (long)row * KD + kb;
    unsigned lo = pack4_fp8(sa[0] - sb[0], sa[1] - sb[1], sa[2] - sb[2], sa[3] - sb[3]);
    unsigned hi = pack4_fp8(sa[4] - sb[4], sa[5] - sb[5], sa[6] - sb[6], sa[7] - sb[7]);
    W[u] = ((unsigned long long)hi << 32) | lo;
}

// ---------- colsum of in_set (fp32, deterministic 2-stage) ----------
__global__ __launch_bounds__(256) void colsum_in_kernel(const float* __restrict__ in,
                                                        float* __restrict__ parts) {
    __shared__ float sh[256];
    int t = threadIdx.x, blk = blockIdx.x;
    int c = t & 127, half = t >> 7;
    long rbeg = (long)blk * 196 + half;
    long rend = (long)(blk + 1) * 196; if (rend > NPTS) rend = NPTS;
    float s = 0.f;
    for (long r = rbeg; r < rend; r += 2) s += in[r * 128 + c];
    sh[t] = s;
    __syncthreads();
    if (t < 128) parts[blk * 128 + t] = sh[t] + sh[t + 128];
}

// ---------- generic partial reduce: parts[nparts][width] -> out[grid][width] ----------
__global__ void part_reduceW_kernel(const float* __restrict__ parts, int nparts, int width,
                                    int op, float* __restrict__ out) {
    int g = blockIdx.x, t = threadIdx.x;
    int chunk = (nparts + gridDim.x - 1) / gridDim.x;
    int b0 = g * chunk, b1 = b0 + chunk; if (b1 > nparts) b1 = nparts;
    float s = 0.f;  // identity 0 valid for max too: values are post-relu >= 0
    for (int b = b0; b < b1; ++b) {
        float v = parts[(long)b * width + t];
        s = (op == 0) ? (s + v) : fmaxf(s, v);
    }
    out[(long)g * width + t] = s;
}

// ---------- fold 8 partial rows + GEMV: out[j] = (fold_g p3[g][:]) . Bm[j][:] + bias ----------
__global__ __launch_bounds__(64) void gemv_fold_kernel(const float* __restrict__ p3, int dsum,
                                                       const float* __restrict__ Bm,
                                                       const float* __restrict__ bias, int op,
                                                       float* __restrict__ out) {
    int j = blockIdx.x, t = threadIdx.x;
    float acc = 0.f;
    for (int d = t; d < dsum; d += 64) {
        float s = 0.f;
#pragma unroll
        for (int g = 0; g < 8; ++g) {
            float v = p3[(long)g * dsum + d];
            s = (op == 0) ? (s + v) : fmaxf(s, v);
        }
        acc += s * Bm[(long)j * dsum + d];
    }
#pragma unroll
    for (int m = 32; m >= 1; m >>= 1) acc += __shfl_down(acc, m);
    if (t == 0) out[j] = acc + (bias ? bias[j] : 0.0f);
}

// ---------- fused layer (fp8, ZERO-SYNC K-loop): C = X@W^T + c ; LN ; relu ; store ; col-red --
// BM=64, BN=512, 256 threads = 4 waves, wave w owns cols [w*128, w*128+128). acc[4][8].
//  - X: staged into LDS ONCE for the whole block (64x512B = NK*4KB), one __syncthreads total.
//  - W: direct global->register u64 loads from Wpack (contiguous 512B per wave-inst, L2-hot).
//  - K-loop: ds_read(a) + global(b) + 64 MFMA per kstep, NO barriers, NO asm waits, NO sched
//    pins -- compiler software-pipelines freely; 2 independent blocks/CU overlap each other.
// This removes the 8-wave barrier convoy that pinned R2-R10 at ~24-27us per block-round.
template<int KD, bool STORE, int REDOP>  // REDOP 0=sum, 1=max
__global__ __launch_bounds__(256, 2)
void layer_kernel(const unsigned char* __restrict__ Xp, const unsigned long long* __restrict__ Wp,
                  const float* __restrict__ cvec, const float* __restrict__ gvec,
                  const float* __restrict__ bvec, unsigned char* __restrict__ Hout,
                  float* __restrict__ red_out) {
    static_assert(KD % 64 == 0, "");
    constexpr int NK = KD / 64;
    __shared__ __align__(128) char smem[NK * 4096];   // X [NK][64][64] fp8; epilogue reuse

    const int t = threadIdx.x;
    const int lane = t & 63;
    const int wv = t >> 6;           // 0..3 : this wave's 128-col slice
    const int ln15 = lane & 15;
    const int lg = lane >> 4;        // 0..3
    const long row0 = (long)blockIdx.x * 64;

    f32x4 acc[4][8];
#pragma unroll
    for (int i = 0; i < 4; ++i)
#pragma unroll
        for (int j = 0; j < 8; ++j) acc[i][j] = (f32x4){0.f, 0.f, 0.f, 0.f};

    // ---- X prologue: stage the ENTIRE row-tile (NK * 4KB), swizzled source, linear dest ----
    {
        const int sr = t >> 2;       // 0..63
        const int ss = t & 3;
        const char* Xsrc = (const char*)Xp + (row0 + sr) * 64 + ((ss ^ ((sr >> 1) & 3)) * 16);
#pragma unroll
        for (int kt = 0; kt < NK; ++kt)
            async_copy16(Xsrc + (long)kt * (NPTS_PAD * 64), smem + kt * 4096 + t * 16);
    }
    __syncthreads();   // compiler emits vmcnt(0)+barrier: all X resident from here on

    // LDS read: row r, k-subtile sub, k-group lg -> swizzled slot (same involution as staging)
#define RD8X(BASE, r, sub) (*(const long*)((BASE) + (r) * 64 + \
        (((((sub) * 2 + (lg >> 1)) ^ (((r) >> 1) & 3)) * 16) + (lg & 1) * 8)))

    // ---- zero-sync K-loop ----
    const unsigned long long* Wq = Wp + (long)wv * (NK * 16) * 64 + lane;
#pragma unroll
    for (int ks = 0; ks < NK; ++ks) {
        const char* Xs = smem + ks * 4096;
        long a0[4], a1[4];
#pragma unroll
        for (int fm = 0; fm < 4; ++fm) {
            int r = fm * 16 + ln15;
            a0[fm] = RD8X(Xs, r, 0);
            a1[fm] = RD8X(Xs, r, 1);
        }
#pragma unroll
        for (int fn = 0; fn < 8; ++fn) {
            long w0 = (long)Wq[(ks * 16 + fn * 2 + 0) * 64];
            long w1 = (long)Wq[(ks * 16 + fn * 2 + 1) * 64];
#pragma unroll
            for (int fm = 0; fm < 4; ++fm)
                acc[fm][fn] = __builtin_amdgcn_mfma_f32_16x16x32_fp8_fp8(a0[fm], w0, acc[fm][fn], 0, 0, 0);
#pragma unroll
            for (int fm = 0; fm < 4; ++fm)
                acc[fm][fn] = __builtin_amdgcn_mfma_f32_16x16x32_fp8_fp8(a1[fm], w1, acc[fm][fn], 0, 0, 0);
        }
    }
#undef RD8X
    __syncthreads();   // before epilogue reuses LDS

    // ---------------- epilogue (reuses LDS) ----------------
    float* lnred_s = (float*)smem;            // [64][4]
    float* lnred_q = (float*)(smem + 1024);   // [64][4]
    float* lnmv    = (float*)(smem + 2048);   // [64][2]

    const int cbase = wv * 128 + ln15;
    float cv[8], gv[8], bv[8];
#pragma unroll
    for (int fn = 0; fn < 8; ++fn) {
        int col = cbase + fn * 16;
        cv[fn] = cvec[col]; gv[fn] = gvec[col]; bv[fn] = bvec[col];
    }

    // add the broadcast c-vector (fp32-exact common term)
#pragma unroll
    for (int fm = 0; fm < 4; ++fm)
#pragma unroll
        for (int fn = 0; fn < 8; ++fn) acc[fm][fn] += cv[fn];

    // per-row sum / sumsq over this wave's 128 cols (shfl tree within 16-lane group)
    float rs[16], rq[16];
#pragma unroll
    for (int fm = 0; fm < 4; ++fm)
#pragma unroll
        for (int j = 0; j < 4; ++j) {
            float s = 0.f, q = 0.f;
#pragma unroll
            for (int fn = 0; fn < 8; ++fn) {
                float x = acc[fm][fn][j];
                s += x; q += x * x;
            }
            rs[fm * 4 + j] = s; rq[fm * 4 + j] = q;
        }
#pragma unroll
    for (int m = 1; m < 16; m <<= 1)
#pragma unroll
        for (int i = 0; i < 16; ++i) {
            rs[i] += __shfl_xor(rs[i], m);
            rq[i] += __shfl_xor(rq[i], m);
        }
    if (ln15 == 0) {
#pragma unroll
        for (int fm = 0; fm < 4; ++fm)
#pragma unroll
            for (int j = 0; j < 4; ++j) {
                int row = fm * 16 + lg * 4 + j;
                lnred_s[row * 4 + wv] = rs[fm * 4 + j];
                lnred_q[row * 4 + wv] = rq[fm * 4 + j];
            }
    }
    __syncthreads();
    if (t < 64) {
        float s = lnred_s[t * 4] + lnred_s[t * 4 + 1] + lnred_s[t * 4 + 2] + lnred_s[t * 4 + 3];
        float q = lnred_q[t * 4] + lnred_q[t * 4 + 1] + lnred_q[t * 4 + 2] + lnred_q[t * 4 + 3];
        float mu = s * (1.0f / 512.0f);
        float var = q * (1.0f / 512.0f) - mu * mu;
        lnmv[t * 2] = mu;
        lnmv[t * 2 + 1] = rsqrtf(var + EPSV);
    }
    __syncthreads();

    // normalize + relu + (store fp8 packed) ; invalid rows forced to 0 (masked)
#pragma unroll
    for (int fm = 0; fm < 4; ++fm)
#pragma unroll
        for (int j = 0; j < 4; ++j) {
            int rloc = fm * 16 + lg * 4 + j;
            long rglob = row0 + rloc;
            bool ok = rglob < NPTS;
            float mu = lnmv[rloc * 2], rstd = lnmv[rloc * 2 + 1];
#pragma unroll
            for (int fn = 0; fn < 8; ++fn) {
                float y = fmaxf((acc[fm][fn][j] - mu) * rstd * gv[fn] + bv[fn], 0.0f);
                acc[fm][fn][j] = ok ? y : 0.0f;
            }
            if (STORE && ok) {
                // col = wv*128 + fn*16 + ln15 -> kt = wv*2 + (fn>>2), byte = (fn&3)*16 + ln15
#pragma unroll
                for (int p = 0; p < 4; ++p) {
                    unsigned u = (unsigned)__builtin_amdgcn_cvt_pk_fp8_f32(
                        acc[fm][2 * p][j], acc[fm][2 * p + 1][j], 0, false);
                    int fnA = 2 * p, fnB = 2 * p + 1;
                    Hout[((long)(wv * 2 + (fnA >> 2)) * NPTS_PAD + rglob) * 64 +
                         (fnA & 3) * 16 + ln15] = (unsigned char)(u & 0xff);
                    Hout[((long)(wv * 2 + (fnB >> 2)) * NPTS_PAD + rglob) * 64 +
                         (fnB & 3) * 16 + ln15] = (unsigned char)((u >> 8) & 0xff);
                }
            }
        }

    // column partials over the block's 64 rows (sum or max); cols disjoint across waves
    float cp[8];
#pragma unroll
    for (int fn = 0; fn < 8; ++fn) {
        float p = 0.f;
#pragma unroll
        for (int fm = 0; fm < 4; ++fm)
#pragma unroll
            for (int j = 0; j < 4; ++j) {
                float v = acc[fm][fn][j];
                p = (REDOP == 0) ? (p + v) : fmaxf(p, v);
            }
        cp[fn] = p;
    }
#pragma unroll
    for (int m = 16; m < 64; m <<= 1)
#pragma unroll
        for (int fn = 0; fn < 8; ++fn) {
            float o = __shfl_xor(cp[fn], m);
            cp[fn] = (REDOP == 0) ? (cp[fn] + o) : fmaxf(cp[fn], o);
        }
    if (lane < 16) {
#pragma unroll
        for (int fn = 0; fn < 8; ++fn)
            red_out[(long)blockIdx.x * 512 + wv * 128 + fn * 16 + lane] = cp[fn];
    }
}

extern "C" void kernel_launch(void* const* d_in, const int* in_sizes, int n_in,
                              void* d_out, int out_size, void* d_ws, size_t ws_size,
                              hipStream_t stream) {
    const float* in_set = (const float*)d_in[0];
    const float* A0 = (const float*)d_in[1];
    const float* B0 = (const float*)d_in[2];
    const float* A1 = (const float*)d_in[3];
    const float* B1 = (const float*)d_in[4];
    const float* A2 = (const float*)d_in[5];
    const float* B2 = (const float*)d_in[6];
    const float* ga = (const float*)d_in[7];
    const float* be = (const float*)d_in[8];
    const float* ow = (const float*)d_in[9];
    const float* ob = (const float*)d_in[10];
    float* outp = (float*)d_out;
    char* ws = (char*)d_ws;

    unsigned char* in_f8 = (unsigned char*)(ws + OFF_INBF);
    unsigned long long* W0p = (unsigned long long*)(ws + OFF_W0);
    unsigned long long* W1p = (unsigned long long*)(ws + OFF_W1);
    unsigned long long* W2p = (unsigned long long*)(ws + OFF_W2);
    float* c0 = (float*)(ws + OFF_C0);
    float* c1 = (float*)(ws + OFF_C1);
    float* c2 = (float*)(ws + OFF_C2);
    float* parts = (float*)(ws + OFF_PARTS);
    float* parts2 = (float*)(ws + OFF_PARTS2);
    float* parts3 = (float*)(ws + OFF_PARTS3);
    unsigned char* h1 = (unsigned char*)(ws + OFF_H1);
    unsigned char* h2 = (unsigned char*)(ws + OFF_H2);

    const int nblk = (NPTS + 63) / 64;  // 1563

    cvt_pack_kernel<<<1024, 256, 0, stream>>>(in_set, in_f8);
    wpack_all_kernel<<<288, 256, 0, stream>>>(A0, B0, A1, B1, A2, B2, W0p, W1p, W2p);

    // c0 = colsum(in_set) @ B0^T  (all fp32 — the numerically critical path)
    colsum_in_kernel<<<512, 256, 0, stream>>>(in_set, parts);                       // [512][128]
    part_reduceW_kernel<<<64, 128, 0, stream>>>(parts, 512, 128, 0, parts2);        // [64][128]
    part_reduceW_kernel<<<8, 128, 0, stream>>>(parts2, 64, 128, 0, parts3);         // [8][128]
    gemv_fold_kernel<<<512, 64, 0, stream>>>(parts3, 128, B0, nullptr, 0, c0);

    layer_kernel<128, true, 0><<<nblk, 256, 0, stream>>>(in_f8, W0p, c0, ga, be, h1, parts);
    part_reduceW_kernel<<<64, 512, 0, stream>>>(parts, nblk, 512, 0, parts2);
    part_reduceW_kernel<<<8, 512, 0, stream>>>(parts2, 64, 512, 0, parts3);
    gemv_fold_kernel<<<512, 64, 0, stream>>>(parts3, 512, B1, nullptr, 0, c1);

    layer_kernel<512, true, 0><<<nblk, 256, 0, stream>>>(h1, W1p, c1, ga, be, h2, parts);
    part_reduceW_kernel<<<64, 512, 0, stream>>>(parts, nblk, 512, 0, parts2);
    part_reduceW_kernel<<<8, 512, 0, stream>>>(parts2, 64, 512, 0, parts3);
    gemv_fold_kernel<<<512, 64, 0, stream>>>(parts3, 512, B2, nullptr, 0, c2);

    // layer 2: no h3 store; fused column-max partials; final = (max-fold) @ ow^T + ob
    layer_kernel<512, false, 1><<<nblk, 256, 0, stream>>>(h2, W2p, c2, ga, be, nullptr, parts);
    part_reduceW_kernel<<<64, 512, 0, stream>>>(parts, nblk, 512, 1, parts2);
    part_reduceW_kernel<<<8, 512, 0, stream>>>(parts2, 64, 512, 1, parts3);
    gemv_fold_kernel<<<256, 64, 0, stream>>>(parts3, 512, ow, ob, 1, outp);
}